// Round 13
// baseline (1467.518 us; speedup 1.0000x reference)
//
#include <hip/hip_runtime.h>
#include <cstddef>

#define HH 256
#define WW 256
#define NB 4
#define NFC 64
#define EMBC 512

typedef short s16x8 __attribute__((ext_vector_type(8)));
typedef float f32x4 __attribute__((ext_vector_type(4)));

#define GLOBAL_AS __attribute__((address_space(1)))
#define LDS_AS __attribute__((address_space(3)))

static __device__ __forceinline__ unsigned short f2b(float f) {
    unsigned int u = __float_as_uint(f);
    u += 0x7FFFu + ((u >> 16) & 1u);
    return (unsigned short)(u >> 16);
}

// ---------------------------------------------------------------------------
// Modulated weights (3 blocks in one launch) -> bf16 [b][tap][co][ci]
// ---------------------------------------------------------------------------
__global__ void modw3_kernel(
    const float* __restrict__ emb,
    const float* __restrict__ mw0, const float* __restrict__ mb0, const float* __restrict__ bw0,
    const float* __restrict__ mw1, const float* __restrict__ mb1, const float* __restrict__ bw1,
    const float* __restrict__ mw2, const float* __restrict__ mb2, const float* __restrict__ bw2,
    unsigned short* __restrict__ outw, size_t ostride)
{
    const int co = blockIdx.x, b = blockIdx.y;
    const int ci = threadIdx.x;
    const float *mw, *mb, *bw;
    switch (blockIdx.z) {
        case 0:  mw = mw0; mb = mb0; bw = bw0; break;
        case 1:  mw = mw1; mb = mb1; bw = bw1; break;
        default: mw = mw2; mb = mb2; bw = bw2; break;
    }

    const float* e = emb + (size_t)b * EMBC;
    const float* m = mw + (size_t)ci * EMBC;
    float s = mb[ci];
    for (int k = 0; k < EMBC; k += 4) {
        float4 ev = *(const float4*)(e + k);
        float4 mv = *(const float4*)(m + k);
        s += ev.x * mv.x + ev.y * mv.y + ev.z * mv.z + ev.w * mv.w;
    }

    float w[9];
    float ss = 0.f;
    const float* src = bw + ((size_t)co * NFC + ci) * 9;
#pragma unroll
    for (int k = 0; k < 9; ++k) {
        float v = (1.0f / 24.0f) * src[k] * s;
        w[k] = v;
        ss += v * v;
    }
#pragma unroll
    for (int off = 32; off; off >>= 1) ss += __shfl_xor(ss, off);
    float demod = rsqrtf(ss + 1e-8f);

    unsigned short* o = outw + (size_t)blockIdx.z * ostride;
#pragma unroll
    for (int k = 0; k < 9; ++k)
        o[(((size_t)b * 9 + k) * NFC + co) * NFC + ci] = f2b(w[k] * demod);
}

// ---------------------------------------------------------------------------
// Fixed-weight transform, 8 tensors in one launch.
// ---------------------------------------------------------------------------
__global__ void fixw8_kernel(
    const float* __restrict__ w0, const float* __restrict__ w1,
    const float* __restrict__ w2, const float* __restrict__ w3,
    const float* __restrict__ w4, const float* __restrict__ w5,
    const float* __restrict__ w6, const float* __restrict__ w7,
    unsigned short* __restrict__ wt)
{
    const int idx = blockIdx.x * 256 + threadIdx.x;
    const float* w;
    switch (blockIdx.y) {
        case 0: w = w0; break;  case 1: w = w1; break;
        case 2: w = w2; break;  case 3: w = w3; break;
        case 4: w = w4; break;  case 5: w = w5; break;
        case 6: w = w6; break;  default: w = w7; break;
    }
    const int k = idx / (NFC * NFC);
    const int rem = idx - k * (NFC * NFC);
    const int co = rem / NFC, ci = rem - co * NFC;
    wt[(size_t)blockIdx.y * 9 * NFC * NFC + idx] = f2b(w[((size_t)co * NFC + ci) * 9 + k]);
}

// ---------------------------------------------------------------------------
__global__ void fixw_last_kernel(const float* __restrict__ w, unsigned short* __restrict__ wt)
{
    int idx = blockIdx.x * 256 + threadIdx.x;
    if (idx >= 9 * 16 * NFC) return;
    int k = idx / (16 * NFC);
    int rem = idx - k * (16 * NFC);
    int co = rem / NFC, ci = rem - co * NFC;
    float v = (co < 3) ? w[((size_t)co * NFC + ci) * 9 + k] : 0.f;
    wt[idx] = f2b(v);
}

// ---------------------------------------------------------------------------
__global__ void firstw_kernel(const float* __restrict__ w, unsigned short* __restrict__ wt)
{
    int idx = blockIdx.x * 256 + threadIdx.x;   // 64*32
    if (idx >= 64 * 32) return;
    int co = idx >> 5, k = idx & 31;
    wt[idx] = (k < 27) ? f2b(w[co * 27 + k]) : 0;
}

// ---------------------------------------------------------------------------
// Layer 0 fused: halo->LDS, im2col->LDS, K=32 MFMA, bf16 NHWC out.
// ---------------------------------------------------------------------------
__global__ __launch_bounds__(256) void conv_first_fused(
    const float* __restrict__ x, const unsigned short* __restrict__ wt,
    const float* __restrict__ bias, unsigned short* __restrict__ out)
{
    __shared__ float xf[3][18][20];
    __shared__ unsigned short col[256][36];

    const int tid = threadIdx.x;
    const int flat = blockIdx.x;
    const int swz = (flat & 7) * 128 + (flat >> 3);
    const int b = swz >> 8, remb = swz & 255;
    const int h0 = (remb >> 4) * 16, w0 = (remb & 15) * 16;

    const int lane = tid & 63, wid = tid >> 6;
    const int m16 = lane & 15, kg = lane >> 4;

    s16x8 a[4];
    float4 bv[4];
#pragma unroll
    for (int mf = 0; mf < 4; ++mf) {
        a[mf] = *(const s16x8*)(wt + (mf * 16 + m16) * 32 + kg * 8);
        bv[mf] = *(const float4*)(bias + mf * 16 + kg * 4);
    }

#pragma unroll 1
    for (int idx = tid; idx < 972; idx += 256) {
        const int ci = idx / 324, rem2 = idx - ci * 324;
        const int row = rem2 / 18, colw = rem2 - row * 18;
        const int gh = h0 + row - 1, gw = w0 + colw - 1;
        float v = 0.f;
        if ((unsigned)gh < HH && (unsigned)gw < WW)
            v = x[(((size_t)b * 3 + ci) * HH + gh) * WW + gw];
        xf[ci][row][colw] = v;
    }
    __syncthreads();

    {
        const int h = tid >> 4, w = tid & 15;
        unsigned short kv[32];
#pragma unroll
        for (int ci = 0; ci < 3; ++ci)
#pragma unroll
            for (int kh = 0; kh < 3; ++kh)
#pragma unroll
                for (int kw = 0; kw < 3; ++kw)
                    kv[ci * 9 + kh * 3 + kw] = f2b(xf[ci][h + kh][w + kw]);
#pragma unroll
        for (int k = 27; k < 32; ++k) kv[k] = 0;
#pragma unroll
        for (int q = 0; q < 4; ++q)
            *(uint4*)&col[tid][q * 8] = *(const uint4*)(kv + q * 8);
    }
    __syncthreads();

#pragma unroll
    for (int t = 0; t < 4; ++t) {
        const int p = wid * 64 + t * 16 + m16;
        s16x8 bfr = *(const s16x8*)&col[p][kg * 8];
#pragma unroll
        for (int mf = 0; mf < 4; ++mf) {
            f32x4 c = (f32x4)(0.f);
            c = __builtin_amdgcn_mfma_f32_16x16x32_bf16(a[mf], bfr, c, 0, 0, 0);
            unsigned short pk[4];
#pragma unroll
            for (int e = 0; e < 4; ++e) {
                float v = c[e] + (&bv[mf].x)[e];
                v = v >= 0.f ? v : 0.1f * v;
                pk[e] = f2b(v);
            }
            const int h = h0 + (p >> 4), w = w0 + (p & 15);
            *(ushort4*)(out + (((size_t)b * HH + h) * WW + w) * NFC + mf * 16 + kg * 4)
                = *(ushort4*)pk;
        }
    }
}

// ---------------------------------------------------------------------------
// Persistent MFMA conv v4 (round 13): block = 32x32 region = 2 vertical
// 32x16 pairs. Wave = 64co x 4 rows (8 waves x 4 = 32 rows): A(4)+B(4) frags
// per g for 16 MFMAs = 0.5 KB/MFMA LDS traffic (vs 0.75 in round 11).
// A-weights from GLOBAL (L2-hot) with parity prefetch depth 2 (live only in
// g-loop: no round-12 spill). LDS = 2 x 78.3 KB pair halos; no weight LDS.
// ---------------------------------------------------------------------------
template <int MFW, bool PERB, bool BIAS, bool LRELU, bool NOISE, bool OUTF32>
__global__ __launch_bounds__(512, 1) void mconv(
    const unsigned short* __restrict__ in, const unsigned short* __restrict__ wt,
    const float* __restrict__ bias, const float* __restrict__ noise,
    const float* __restrict__ wnp, void* __restrict__ outv)
{
    constexpr int COPW = MFW * 16;                // co covered (64 main, 16 last)
    constexpr int WELEM = 9 * 64 * NFC;           // per-batch stride (main layers)
    __shared__ uint4 xs[2][34 * 18 * 8];          // 2 x 78336 B

    const int tid = threadIdx.x;
    const int lane = tid & 63, wid = tid >> 6;    // wid 0..7 = row-group
    const int m16 = lane & 15, kg = lane >> 4;

    const int hw = blockIdx.x;                    // 0..255
    const int n = (hw & 7) * 32 + (hw >> 3);      // XCD-chunked logical id
    const int b = n >> 6;                         // image
    const int reg_ = n & 63;
    const int rh = reg_ >> 3, rw = reg_ & 7;      // 8x8 regions of 32x32 px
    const int h0r = rh * 32;

    const unsigned short* wsrc = PERB ? wt + (size_t)b * WELEM : wt;
    const unsigned short* wlane = wsrc + m16 * NFC + kg * 8;

    // stage one 32x16 pair (halo 34x18) into buf
    auto stage_pair = [&](int p, uint4* buf) {
        const int w0p = rw * 32 + p * 16;
        const bool interior = (rh > 0) && (rh < 7)
                              && !(rw == 0 && p == 0) && !(rw == 7 && p == 1);
        if (interior) {
            for (int i = wid; i < 102; i += 8) {          // 34 rows x 3 parts
                const int row = i / 3, part = i - row * 3;
                const int j0 = (part == 0) ? -1 : (part == 1) ? 7 : 9;
                const int gh = h0r + row - 1;
                const int j = j0 + (lane >> 3);
                const int gw = w0p + j;
                const int w = j + 1;
                const unsigned short* gp = in + (((size_t)b * HH + gh) * WW + gw) * NFC
                                              + ((lane & 7) ^ (w & 7)) * 8;
                uint4* lp = buf + (size_t)(row * 18 + (j0 + 1)) * 8;
                __builtin_amdgcn_global_load_lds(
                    (const GLOBAL_AS void*)gp, (LDS_AS void*)lp, 16, 0, 0);
            }
        } else {
#pragma unroll 1
            for (int idx = tid; idx < 4896; idx += 512) { // 34*18*8
                const int row = idx / 144, rem2 = idx - row * 144;
                const int w = rem2 >> 3, slot = rem2 & 7;
                const int gh = h0r + row - 1, gw = w0p + w - 1;
                uint4 u = make_uint4(0, 0, 0, 0);
                if ((unsigned)gh < HH && (unsigned)gw < WW)
                    u = *(const uint4*)(in + (((size_t)b * HH + gh) * WW + gw) * NFC + slot * 8);
                buf[(row * 18 + w) * 8 + (slot ^ (w & 7))] = u;
            }
        }
    };

    const float wn = NOISE ? wnp[0] : 0.f;

    stage_pair(0, xs[0]);
    __syncthreads();                              // pair0 staged

#pragma unroll 1
    for (int p = 0; p < 2; ++p) {
        const uint4* buf = xs[p];
        const int w0p = rw * 32 + p * 16;

        if (p == 0) stage_pair(1, xs[1]);         // overlap with pair0 compute

        f32x4 acc[MFW][4];
#pragma unroll
        for (int mf = 0; mf < MFW; ++mf)
#pragma unroll
            for (int r = 0; r < 4; ++r) acc[mf][r] = (f32x4)(0.f);

        s16x8 abuf[2][MFW];
        s16x8 bbuf[2][4];

        auto LOADA = [&](int g, int par) {
            const unsigned short* pp = wlane + (size_t)(g >> 1) * (COPW * NFC) + (g & 1) * 32;
#pragma unroll
            for (int mf = 0; mf < MFW; ++mf)
                abuf[par][mf] = *(const s16x8*)(pp + mf * 16 * NFC);
        };
        auto LOADB = [&](int g, int par) {
            const int tap = g >> 1, half = g & 1;
            const int kh = tap / 3, kw = tap - kh * 3;
            const int lw = m16 + kw;
            const int slot = (half * 4 + kg) ^ (lw & 7);
#pragma unroll
            for (int r = 0; r < 4; ++r) {
                const int lrow = wid * 4 + r + kh;         // 0..33
                bbuf[par][r] = *(const s16x8*)&buf[(lrow * 18 + lw) * 8 + slot];
            }
        };

        LOADA(0, 0); LOADB(0, 0);
#pragma unroll
        for (int g = 0; g < 18; ++g) {
            if (g + 1 < 18) { LOADA(g + 1, (g + 1) & 1); LOADB(g + 1, (g + 1) & 1); }
#pragma unroll
            for (int r = 0; r < 4; ++r)
#pragma unroll
                for (int mf = 0; mf < MFW; ++mf)
                    acc[mf][r] = __builtin_amdgcn_mfma_f32_16x16x32_bf16(
                        abuf[g & 1][mf], bbuf[g & 1][r], acc[mf][r], 0, 0, 0);
        }

        // ---- epilogue: wave owns rows wid*4..+3 of the 32-row pair ----
        const int wcol = w0p + m16;
#pragma unroll
        for (int r = 0; r < 4; ++r) {
            const int h = h0r + wid * 4 + r;
            float nz = 0.f;
            if (NOISE) nz = noise[((size_t)b * HH + h) * WW + wcol];
#pragma unroll
            for (int mf = 0; mf < MFW; ++mf) {
                const int cob = mf * 16 + kg * 4;
                f32x4 v = acc[mf][r];
                float4 bvv = make_float4(0.f, 0.f, 0.f, 0.f);
                if (BIAS) bvv = *(const float4*)(bias + cob);
                float o[4];
#pragma unroll
                for (int e = 0; e < 4; ++e) {
                    float t = v[e] + (BIAS ? (&bvv.x)[e] : 0.f);
                    if (NOISE) t += wn * nz;
                    if (LRELU) t = t >= 0.f ? t : 0.1f * t;
                    o[e] = t;
                }
                if (OUTF32) {
                    float* of = (float*)outv;
#pragma unroll
                    for (int e = 0; e < 4; ++e) {
                        int co = cob + e;
                        if (co < 3)
                            of[(((size_t)b * 3 + co) * HH + h) * WW + wcol] = o[e];
                    }
                } else {
                    unsigned short pk[4];
#pragma unroll
                    for (int e = 0; e < 4; ++e) pk[e] = f2b(o[e]);
                    unsigned short* ob = (unsigned short*)outv;
                    *(ushort4*)(ob + (((size_t)b * HH + h) * WW + wcol) * NFC + cob) = *(ushort4*)pk;
                }
            }
        }
        __syncthreads();   // drains pair1 DMA before its compute
    }
}

// ---------------------------------------------------------------------------
extern "C" void kernel_launch(void* const* d_in, const int* in_sizes, int n_in,
                              void* d_out, int out_size, void* d_ws, size_t ws_size,
                              hipStream_t stream)
{
    auto F = [&](int i) { return (const float*)d_in[i]; };
    const float* x       = F(0);
    const float* emb     = F(1);
    const float* noise[3] = {F(2), F(3), F(4)};
    const float* w_first = F(5);  const float* b_first = F(6);
    const float* w_hr[5] = {F(7), F(9), F(11), F(13), F(15)};
    const float* b_hr[5] = {F(8), F(10), F(12), F(14), F(16)};
    const float* w_last  = F(17); const float* b_last = F(18);
    const float *m_mw[3], *m_mb[3], *m_w[3], *m_cw[3], *m_cb[3], *m_wn[3];
    for (int i = 0; i < 3; ++i) {
        int o = 19 + 6 * i;
        m_mw[i] = F(o); m_mb[i] = F(o + 1); m_w[i] = F(o + 2);
        m_cw[i] = F(o + 3); m_cb[i] = F(o + 4); m_wn[i] = F(o + 5);
    }

    const size_t ACT  = (size_t)NB * HH * WW * NFC;
    const size_t MODW = (size_t)NB * 9 * NFC * NFC;
    const size_t FIXW = (size_t)9 * NFC * NFC;
    unsigned short* act0 = (unsigned short*)d_ws;
    unsigned short* act1 = act0 + ACT;
    unsigned short* wmod = act1 + ACT;
    unsigned short* wfix = wmod + 3 * MODW;
    unsigned short* wlast = wfix + 8 * FIXW;
    unsigned short* wfirst = wlast + 9 * 16 * NFC;

    modw3_kernel<<<dim3(NFC, NB, 3), NFC, 0, stream>>>(
        emb, m_mw[0], m_mb[0], m_w[0], m_mw[1], m_mb[1], m_w[1],
        m_mw[2], m_mb[2], m_w[2], wmod, MODW);
    fixw8_kernel<<<dim3(144, 8), 256, 0, stream>>>(
        m_cw[0], m_cw[1], m_cw[2], w_hr[0], w_hr[1], w_hr[2], w_hr[3], w_hr[4], wfix);
    fixw_last_kernel<<<(9 * 16 * 64 + 255) / 256, 256, 0, stream>>>(w_last, wlast);
    firstw_kernel<<<8, 256, 0, stream>>>(w_first, wfirst);

    conv_first_fused<<<1024, 256, 0, stream>>>(x, wfirst, b_first, act0);

    const int grid = 256;
    unsigned short* cur = act0;
    unsigned short* nxt = act1;
    auto swap = [&]() { unsigned short* t = cur; cur = nxt; nxt = t; };

    for (int i = 0; i < 3; ++i) {
        mconv<4, true, false, false, true, false>
            <<<grid, 512, 0, stream>>>(cur, wmod + i * MODW, nullptr, noise[i], m_wn[i], nxt);
        swap();
        mconv<4, false, true, true, false, false>
            <<<grid, 512, 0, stream>>>(cur, wfix + i * FIXW, m_cb[i], nullptr, nullptr, nxt);
        swap();
        mconv<4, false, true, false, false, false>
            <<<grid, 512, 0, stream>>>(cur, wfix + (3 + i) * FIXW, b_hr[i], nullptr, nullptr, nxt);
        swap();
    }
    mconv<4, false, true, false, false, false>
        <<<grid, 512, 0, stream>>>(cur, wfix + 6 * FIXW, b_hr[3], nullptr, nullptr, nxt);
    swap();
    mconv<4, false, true, false, false, false>
        <<<grid, 512, 0, stream>>>(cur, wfix + 7 * FIXW, b_hr[4], nullptr, nullptr, nxt);
    swap();
    mconv<1, false, true, false, false, true>
        <<<grid, 512, 0, stream>>>(cur, wlast, b_last, nullptr, nullptr, d_out);
}

// Round 14
// 411.331 us; speedup vs baseline: 3.5677x; 3.5677x over previous
//
#include <hip/hip_runtime.h>
#include <cstddef>

#define HH 256
#define WW 256
#define NB 4
#define NFC 64
#define EMBC 512

typedef short s16x8 __attribute__((ext_vector_type(8)));
typedef float f32x4 __attribute__((ext_vector_type(4)));

#define GLOBAL_AS __attribute__((address_space(1)))
#define LDS_AS __attribute__((address_space(3)))

static __device__ __forceinline__ unsigned short f2b(float f) {
    unsigned int u = __float_as_uint(f);
    u += 0x7FFFu + ((u >> 16) & 1u);
    return (unsigned short)(u >> 16);
}

// ---------------------------------------------------------------------------
// Modulated weights (3 blocks in one launch) -> bf16 [b][tap][co][ci]
// ---------------------------------------------------------------------------
__global__ void modw3_kernel(
    const float* __restrict__ emb,
    const float* __restrict__ mw0, const float* __restrict__ mb0, const float* __restrict__ bw0,
    const float* __restrict__ mw1, const float* __restrict__ mb1, const float* __restrict__ bw1,
    const float* __restrict__ mw2, const float* __restrict__ mb2, const float* __restrict__ bw2,
    unsigned short* __restrict__ outw, size_t ostride)
{
    const int co = blockIdx.x, b = blockIdx.y;
    const int ci = threadIdx.x;
    const float *mw, *mb, *bw;
    switch (blockIdx.z) {
        case 0:  mw = mw0; mb = mb0; bw = bw0; break;
        case 1:  mw = mw1; mb = mb1; bw = bw1; break;
        default: mw = mw2; mb = mb2; bw = bw2; break;
    }

    const float* e = emb + (size_t)b * EMBC;
    const float* m = mw + (size_t)ci * EMBC;
    float s = mb[ci];
    for (int k = 0; k < EMBC; k += 4) {
        float4 ev = *(const float4*)(e + k);
        float4 mv = *(const float4*)(m + k);
        s += ev.x * mv.x + ev.y * mv.y + ev.z * mv.z + ev.w * mv.w;
    }

    float w[9];
    float ss = 0.f;
    const float* src = bw + ((size_t)co * NFC + ci) * 9;
#pragma unroll
    for (int k = 0; k < 9; ++k) {
        float v = (1.0f / 24.0f) * src[k] * s;
        w[k] = v;
        ss += v * v;
    }
#pragma unroll
    for (int off = 32; off; off >>= 1) ss += __shfl_xor(ss, off);
    float demod = rsqrtf(ss + 1e-8f);

    unsigned short* o = outw + (size_t)blockIdx.z * ostride;
#pragma unroll
    for (int k = 0; k < 9; ++k)
        o[(((size_t)b * 9 + k) * NFC + co) * NFC + ci] = f2b(w[k] * demod);
}

// ---------------------------------------------------------------------------
// Fixed-weight transform, 8 tensors in one launch.
// ---------------------------------------------------------------------------
__global__ void fixw8_kernel(
    const float* __restrict__ w0, const float* __restrict__ w1,
    const float* __restrict__ w2, const float* __restrict__ w3,
    const float* __restrict__ w4, const float* __restrict__ w5,
    const float* __restrict__ w6, const float* __restrict__ w7,
    unsigned short* __restrict__ wt)
{
    const int idx = blockIdx.x * 256 + threadIdx.x;
    const float* w;
    switch (blockIdx.y) {
        case 0: w = w0; break;  case 1: w = w1; break;
        case 2: w = w2; break;  case 3: w = w3; break;
        case 4: w = w4; break;  case 5: w = w5; break;
        case 6: w = w6; break;  default: w = w7; break;
    }
    const int k = idx / (NFC * NFC);
    const int rem = idx - k * (NFC * NFC);
    const int co = rem / NFC, ci = rem - co * NFC;
    wt[(size_t)blockIdx.y * 9 * NFC * NFC + idx] = f2b(w[((size_t)co * NFC + ci) * 9 + k]);
}

// ---------------------------------------------------------------------------
__global__ void fixw_last_kernel(const float* __restrict__ w, unsigned short* __restrict__ wt)
{
    int idx = blockIdx.x * 256 + threadIdx.x;
    if (idx >= 9 * 16 * NFC) return;
    int k = idx / (16 * NFC);
    int rem = idx - k * (16 * NFC);
    int co = rem / NFC, ci = rem - co * NFC;
    float v = (co < 3) ? w[((size_t)co * NFC + ci) * 9 + k] : 0.f;
    wt[idx] = f2b(v);
}

// ---------------------------------------------------------------------------
__global__ void firstw_kernel(const float* __restrict__ w, unsigned short* __restrict__ wt)
{
    int idx = blockIdx.x * 256 + threadIdx.x;   // 64*32
    if (idx >= 64 * 32) return;
    int co = idx >> 5, k = idx & 31;
    wt[idx] = (k < 27) ? f2b(w[co * 27 + k]) : 0;
}

// ---------------------------------------------------------------------------
// Layer 0 fused: halo->LDS, im2col->LDS, K=32 MFMA, bf16 NHWC out.
// ---------------------------------------------------------------------------
__global__ __launch_bounds__(256) void conv_first_fused(
    const float* __restrict__ x, const unsigned short* __restrict__ wt,
    const float* __restrict__ bias, unsigned short* __restrict__ out)
{
    __shared__ float xf[3][18][20];
    __shared__ unsigned short col[256][36];

    const int tid = threadIdx.x;
    const int flat = blockIdx.x;
    const int swz = (flat & 7) * 128 + (flat >> 3);
    const int b = swz >> 8, remb = swz & 255;
    const int h0 = (remb >> 4) * 16, w0 = (remb & 15) * 16;

    const int lane = tid & 63, wid = tid >> 6;
    const int m16 = lane & 15, kg = lane >> 4;

    s16x8 a[4];
    float4 bv[4];
#pragma unroll
    for (int mf = 0; mf < 4; ++mf) {
        a[mf] = *(const s16x8*)(wt + (mf * 16 + m16) * 32 + kg * 8);
        bv[mf] = *(const float4*)(bias + mf * 16 + kg * 4);
    }

#pragma unroll 1
    for (int idx = tid; idx < 972; idx += 256) {
        const int ci = idx / 324, rem2 = idx - ci * 324;
        const int row = rem2 / 18, colw = rem2 - row * 18;
        const int gh = h0 + row - 1, gw = w0 + colw - 1;
        float v = 0.f;
        if ((unsigned)gh < HH && (unsigned)gw < WW)
            v = x[(((size_t)b * 3 + ci) * HH + gh) * WW + gw];
        xf[ci][row][colw] = v;
    }
    __syncthreads();

    {
        const int h = tid >> 4, w = tid & 15;
        unsigned short kv[32];
#pragma unroll
        for (int ci = 0; ci < 3; ++ci)
#pragma unroll
            for (int kh = 0; kh < 3; ++kh)
#pragma unroll
                for (int kw = 0; kw < 3; ++kw)
                    kv[ci * 9 + kh * 3 + kw] = f2b(xf[ci][h + kh][w + kw]);
#pragma unroll
        for (int k = 27; k < 32; ++k) kv[k] = 0;
#pragma unroll
        for (int q = 0; q < 4; ++q)
            *(uint4*)&col[tid][q * 8] = *(const uint4*)(kv + q * 8);
    }
    __syncthreads();

#pragma unroll
    for (int t = 0; t < 4; ++t) {
        const int p = wid * 64 + t * 16 + m16;
        s16x8 bfr = *(const s16x8*)&col[p][kg * 8];
#pragma unroll
        for (int mf = 0; mf < 4; ++mf) {
            f32x4 c = (f32x4)(0.f);
            c = __builtin_amdgcn_mfma_f32_16x16x32_bf16(a[mf], bfr, c, 0, 0, 0);
            unsigned short pk[4];
#pragma unroll
            for (int e = 0; e < 4; ++e) {
                float v = c[e] + (&bv[mf].x)[e];
                v = v >= 0.f ? v : 0.1f * v;
                pk[e] = f2b(v);
            }
            const int h = h0 + (p >> 4), w = w0 + (p & 15);
            *(ushort4*)(out + (((size_t)b * HH + h) * WW + w) * NFC + mf * 16 + kg * 4)
                = *(ushort4*)pk;
        }
    }
}

// ---------------------------------------------------------------------------
// Strip MFMA conv (round 14): block = one 16x64 strip (4 tiles, shared halo).
// LDS = single 18x66 halo (148.5 KB). Per g: 1 A-fetch (global, L2-hot)
// feeds 4 tiles x 2 rows = 32 MFMAs -> 0.25 KB LDS-read per MFMA.
// g-loop: #pragma unroll 1 over 9 taps, 2 half-bodies, manual A-prefetch
// via named aA/aB (no hoisting -> no spills). Clamped DMA + zero-fix pass
// replaces the interior/border split entirely.
// ---------------------------------------------------------------------------
template <int MFW, bool PERB, bool BIAS, bool LRELU, bool NOISE, bool OUTF32>
__global__ __launch_bounds__(512, 1) void mconv(
    const unsigned short* __restrict__ in, const unsigned short* __restrict__ wt,
    const float* __restrict__ bias, const float* __restrict__ noise,
    const float* __restrict__ wnp, void* __restrict__ outv)
{
    constexpr int COPW = MFW * 16;                // 64 main, 16 last
    constexpr int WELEM = 9 * COPW * NFC;
    __shared__ uint4 xs[18 * 66 * 8];             // 152064 B

    const int tid = threadIdx.x;
    const int lane = tid & 63, wid = tid >> 6;    // wid 0..7 = row-group
    const int m16 = lane & 15, kg = lane >> 4;

    const int hw = blockIdx.x;                    // 0..255
    const int n = (hw & 7) * 32 + (hw >> 3);      // XCD-chunked logical id
    const int b = n >> 6;                         // image
    const int sr = (n >> 2) & 15;                 // strip row (16 rows each)
    const int cg = n & 3;                         // col group (64 cols each)
    const int h0 = sr * 16, w0 = cg * 64;

    // ---- stage strip halo 18x66 via clamped DMA (uniform path) ----
    for (int i = wid; i < 162; i += 8) {          // 18 rows x 9 parts
        const int row = i / 9, part = i - row * 9;
        const int j0 = (part < 8) ? (part * 8 - 1) : 57;
        int gh = h0 + row - 1;
        gh = gh < 0 ? 0 : (gh > 255 ? 255 : gh);
        const int j = j0 + (lane >> 3);
        int gw = w0 + j;
        gw = gw < 0 ? 0 : (gw > 255 ? 255 : gw);
        const int w = j + 1;                      // LDS w 0..65
        const unsigned short* gp = in + (((size_t)b * HH + gh) * WW + gw) * NFC
                                      + ((lane & 7) ^ (w & 7)) * 8;
        uint4* lp = xs + (size_t)(row * 66 + (j0 + 1)) * 8;
        __builtin_amdgcn_global_load_lds(
            (const GLOBAL_AS void*)gp, (LDS_AS void*)lp, 16, 0, 0);
    }
    __syncthreads();                              // drain DMA

    // ---- zero-fix image-border padding cells ----
    const uint4 z4 = make_uint4(0, 0, 0, 0);
    if (sr == 0)
        for (int idx = tid; idx < 528; idx += 512) xs[idx] = z4;
    if (sr == 15)
        for (int idx = tid; idx < 528; idx += 512) xs[17 * 528 + idx] = z4;
    if (cg == 0)
        for (int idx = tid; idx < 144; idx += 512) xs[(idx >> 3) * 528 + (idx & 7)] = z4;
    if (cg == 3)
        for (int idx = tid; idx < 144; idx += 512) xs[(idx >> 3) * 528 + 520 + (idx & 7)] = z4;
    __syncthreads();

    // ---- compute: all 4 tiles at once ----
    const unsigned short* wsrc = PERB ? wt + (size_t)b * WELEM : wt;
    const unsigned short* wlane = wsrc + m16 * NFC + kg * 8;

    f32x4 acc[4][MFW][2];
#pragma unroll
    for (int t = 0; t < 4; ++t)
#pragma unroll
        for (int mf = 0; mf < MFW; ++mf)
#pragma unroll
            for (int r = 0; r < 2; ++r) acc[t][mf][r] = (f32x4)(0.f);

    s16x8 aA[MFW], aB[MFW];
    auto LOADA = [&](int g, s16x8* a) {
        const unsigned short* p = wlane + (size_t)(g >> 1) * (COPW * NFC) + (g & 1) * 32;
#pragma unroll
        for (int mf = 0; mf < MFW; ++mf)
            a[mf] = *(const s16x8*)(p + mf * 16 * NFC);
    };

    LOADA(0, aA);
#pragma unroll 1
    for (int gg = 0; gg < 9; ++gg) {
        const int kh = gg / 3, kw = gg - kh * 3;
        const int lrow0 = wid * 2 + kh;
        LOADA(2 * gg + 1, aB);                    // prefetch half 1
        {   // half 0 (ci 0..31), uses aA
            const int slot0 = kg;                 // (0*4+kg), ^ (w&7) below
            s16x8 bb[4][2];
#pragma unroll
            for (int t = 0; t < 4; ++t) {
                const int w = t * 16 + m16 + kw;
#pragma unroll
                for (int r = 0; r < 2; ++r)
                    bb[t][r] = *(const s16x8*)&xs[((lrow0 + r) * 66 + w) * 8 + (slot0 ^ (w & 7))];
            }
#pragma unroll
            for (int t = 0; t < 4; ++t)
#pragma unroll
                for (int r = 0; r < 2; ++r)
#pragma unroll
                    for (int mf = 0; mf < MFW; ++mf)
                        acc[t][mf][r] = __builtin_amdgcn_mfma_f32_16x16x32_bf16(
                            aA[mf], bb[t][r], acc[t][mf][r], 0, 0, 0);
        }
        if (gg < 8) LOADA(2 * gg + 2, aA);        // prefetch next half 0
        {   // half 1 (ci 32..63), uses aB
            const int slot1 = 4 + kg;
            s16x8 bb[4][2];
#pragma unroll
            for (int t = 0; t < 4; ++t) {
                const int w = t * 16 + m16 + kw;
#pragma unroll
                for (int r = 0; r < 2; ++r)
                    bb[t][r] = *(const s16x8*)&xs[((lrow0 + r) * 66 + w) * 8 + (slot1 ^ (w & 7))];
            }
#pragma unroll
            for (int t = 0; t < 4; ++t)
#pragma unroll
                for (int r = 0; r < 2; ++r)
#pragma unroll
                    for (int mf = 0; mf < MFW; ++mf)
                        acc[t][mf][r] = __builtin_amdgcn_mfma_f32_16x16x32_bf16(
                            aB[mf], bb[t][r], acc[t][mf][r], 0, 0, 0);
        }
    }

    // ---- epilogue: wave owns rows wid*2..+1 x 64 cols ----
    const float wn = NOISE ? wnp[0] : 0.f;
#pragma unroll
    for (int r = 0; r < 2; ++r) {
        const int h = h0 + wid * 2 + r;
#pragma unroll
        for (int t = 0; t < 4; ++t) {
            const int wcol = w0 + t * 16 + m16;
            float nz = 0.f;
            if (NOISE) nz = noise[((size_t)b * HH + h) * WW + wcol];
#pragma unroll
            for (int mf = 0; mf < MFW; ++mf) {
                const int cob = mf * 16 + kg * 4;
                f32x4 v = acc[t][mf][r];
                float4 bvv = make_float4(0.f, 0.f, 0.f, 0.f);
                if (BIAS) bvv = *(const float4*)(bias + cob);
                float o[4];
#pragma unroll
                for (int e = 0; e < 4; ++e) {
                    float tt = v[e] + (BIAS ? (&bvv.x)[e] : 0.f);
                    if (NOISE) tt += wn * nz;
                    if (LRELU) tt = tt >= 0.f ? tt : 0.1f * tt;
                    o[e] = tt;
                }
                if (OUTF32) {
                    float* of = (float*)outv;
#pragma unroll
                    for (int e = 0; e < 4; ++e) {
                        int co = cob + e;
                        if (co < 3)
                            of[(((size_t)b * 3 + co) * HH + h) * WW + wcol] = o[e];
                    }
                } else {
                    unsigned short pk[4];
#pragma unroll
                    for (int e = 0; e < 4; ++e) pk[e] = f2b(o[e]);
                    unsigned short* ob = (unsigned short*)outv;
                    *(ushort4*)(ob + (((size_t)b * HH + h) * WW + wcol) * NFC + cob) = *(ushort4*)pk;
                }
            }
        }
    }
}

// ---------------------------------------------------------------------------
extern "C" void kernel_launch(void* const* d_in, const int* in_sizes, int n_in,
                              void* d_out, int out_size, void* d_ws, size_t ws_size,
                              hipStream_t stream)
{
    auto F = [&](int i) { return (const float*)d_in[i]; };
    const float* x       = F(0);
    const float* emb     = F(1);
    const float* noise[3] = {F(2), F(3), F(4)};
    const float* w_first = F(5);  const float* b_first = F(6);
    const float* w_hr[5] = {F(7), F(9), F(11), F(13), F(15)};
    const float* b_hr[5] = {F(8), F(10), F(12), F(14), F(16)};
    const float* w_last  = F(17); const float* b_last = F(18);
    const float *m_mw[3], *m_mb[3], *m_w[3], *m_cw[3], *m_cb[3], *m_wn[3];
    for (int i = 0; i < 3; ++i) {
        int o = 19 + 6 * i;
        m_mw[i] = F(o); m_mb[i] = F(o + 1); m_w[i] = F(o + 2);
        m_cw[i] = F(o + 3); m_cb[i] = F(o + 4); m_wn[i] = F(o + 5);
    }

    const size_t ACT  = (size_t)NB * HH * WW * NFC;
    const size_t MODW = (size_t)NB * 9 * NFC * NFC;
    const size_t FIXW = (size_t)9 * NFC * NFC;
    unsigned short* act0 = (unsigned short*)d_ws;
    unsigned short* act1 = act0 + ACT;
    unsigned short* wmod = act1 + ACT;
    unsigned short* wfix = wmod + 3 * MODW;
    unsigned short* wlast = wfix + 8 * FIXW;
    unsigned short* wfirst = wlast + 9 * 16 * NFC;

    modw3_kernel<<<dim3(NFC, NB, 3), NFC, 0, stream>>>(
        emb, m_mw[0], m_mb[0], m_w[0], m_mw[1], m_mb[1], m_w[1],
        m_mw[2], m_mb[2], m_w[2], wmod, MODW);
    fixw8_kernel<<<dim3(144, 8), 256, 0, stream>>>(
        m_cw[0], m_cw[1], m_cw[2], w_hr[0], w_hr[1], w_hr[2], w_hr[3], w_hr[4], wfix);
    fixw_last_kernel<<<(9 * 16 * 64 + 255) / 256, 256, 0, stream>>>(w_last, wlast);
    firstw_kernel<<<8, 256, 0, stream>>>(w_first, wfirst);

    conv_first_fused<<<1024, 256, 0, stream>>>(x, wfirst, b_first, act0);

    const int grid = 256;
    unsigned short* cur = act0;
    unsigned short* nxt = act1;
    auto swap = [&]() { unsigned short* t = cur; cur = nxt; nxt = t; };

    for (int i = 0; i < 3; ++i) {
        mconv<4, true, false, false, true, false>
            <<<grid, 512, 0, stream>>>(cur, wmod + i * MODW, nullptr, noise[i], m_wn[i], nxt);
        swap();
        mconv<4, false, true, true, false, false>
            <<<grid, 512, 0, stream>>>(cur, wfix + i * FIXW, m_cb[i], nullptr, nullptr, nxt);
        swap();
        mconv<4, false, true, false, false, false>
            <<<grid, 512, 0, stream>>>(cur, wfix + (3 + i) * FIXW, b_hr[i], nullptr, nullptr, nxt);
        swap();
    }
    mconv<4, false, true, false, false, false>
        <<<grid, 512, 0, stream>>>(cur, wfix + 6 * FIXW, b_hr[3], nullptr, nullptr, nxt);
    swap();
    mconv<4, false, true, false, false, false>
        <<<grid, 512, 0, stream>>>(cur, wfix + 7 * FIXW, b_hr[4], nullptr, nullptr, nxt);
    swap();
    mconv<1, false, true, false, false, true>
        <<<grid, 512, 0, stream>>>(cur, wlast, b_last, nullptr, nullptr, d_out);
}

// Round 15
// 328.423 us; speedup vs baseline: 4.4684x; 1.2524x over previous
//
#include <hip/hip_runtime.h>
#include <cstddef>

#define HH 256
#define WW 256
#define NB 4
#define NFC 64
#define EMBC 512

typedef short s16x8 __attribute__((ext_vector_type(8)));
typedef float f32x4 __attribute__((ext_vector_type(4)));

#define GLOBAL_AS __attribute__((address_space(1)))
#define LDS_AS __attribute__((address_space(3)))

static __device__ __forceinline__ unsigned short f2b(float f) {
    unsigned int u = __float_as_uint(f);
    u += 0x7FFFu + ((u >> 16) & 1u);
    return (unsigned short)(u >> 16);
}

// ---------------------------------------------------------------------------
// Modulated weights (3 blocks in one launch) -> bf16 [b][tap][co][ci]
// ---------------------------------------------------------------------------
__global__ void modw3_kernel(
    const float* __restrict__ emb,
    const float* __restrict__ mw0, const float* __restrict__ mb0, const float* __restrict__ bw0,
    const float* __restrict__ mw1, const float* __restrict__ mb1, const float* __restrict__ bw1,
    const float* __restrict__ mw2, const float* __restrict__ mb2, const float* __restrict__ bw2,
    unsigned short* __restrict__ outw, size_t ostride)
{
    const int co = blockIdx.x, b = blockIdx.y;
    const int ci = threadIdx.x;
    const float *mw, *mb, *bw;
    switch (blockIdx.z) {
        case 0:  mw = mw0; mb = mb0; bw = bw0; break;
        case 1:  mw = mw1; mb = mb1; bw = bw1; break;
        default: mw = mw2; mb = mb2; bw = bw2; break;
    }

    const float* e = emb + (size_t)b * EMBC;
    const float* m = mw + (size_t)ci * EMBC;
    float s = mb[ci];
    for (int k = 0; k < EMBC; k += 4) {
        float4 ev = *(const float4*)(e + k);
        float4 mv = *(const float4*)(m + k);
        s += ev.x * mv.x + ev.y * mv.y + ev.z * mv.z + ev.w * mv.w;
    }

    float w[9];
    float ss = 0.f;
    const float* src = bw + ((size_t)co * NFC + ci) * 9;
#pragma unroll
    for (int k = 0; k < 9; ++k) {
        float v = (1.0f / 24.0f) * src[k] * s;
        w[k] = v;
        ss += v * v;
    }
#pragma unroll
    for (int off = 32; off; off >>= 1) ss += __shfl_xor(ss, off);
    float demod = rsqrtf(ss + 1e-8f);

    unsigned short* o = outw + (size_t)blockIdx.z * ostride;
#pragma unroll
    for (int k = 0; k < 9; ++k)
        o[(((size_t)b * 9 + k) * NFC + co) * NFC + ci] = f2b(w[k] * demod);
}

// ---------------------------------------------------------------------------
// Fixed-weight transform, 8 tensors in one launch.
// ---------------------------------------------------------------------------
__global__ void fixw8_kernel(
    const float* __restrict__ w0, const float* __restrict__ w1,
    const float* __restrict__ w2, const float* __restrict__ w3,
    const float* __restrict__ w4, const float* __restrict__ w5,
    const float* __restrict__ w6, const float* __restrict__ w7,
    unsigned short* __restrict__ wt)
{
    const int idx = blockIdx.x * 256 + threadIdx.x;
    const float* w;
    switch (blockIdx.y) {
        case 0: w = w0; break;  case 1: w = w1; break;
        case 2: w = w2; break;  case 3: w = w3; break;
        case 4: w = w4; break;  case 5: w = w5; break;
        case 6: w = w6; break;  default: w = w7; break;
    }
    const int k = idx / (NFC * NFC);
    const int rem = idx - k * (NFC * NFC);
    const int co = rem / NFC, ci = rem - co * NFC;
    wt[(size_t)blockIdx.y * 9 * NFC * NFC + idx] = f2b(w[((size_t)co * NFC + ci) * 9 + k]);
}

// ---------------------------------------------------------------------------
__global__ void fixw_last_kernel(const float* __restrict__ w, unsigned short* __restrict__ wt)
{
    int idx = blockIdx.x * 256 + threadIdx.x;
    if (idx >= 9 * 16 * NFC) return;
    int k = idx / (16 * NFC);
    int rem = idx - k * (16 * NFC);
    int co = rem / NFC, ci = rem - co * NFC;
    float v = (co < 3) ? w[((size_t)co * NFC + ci) * 9 + k] : 0.f;
    wt[idx] = f2b(v);
}

// ---------------------------------------------------------------------------
__global__ void firstw_kernel(const float* __restrict__ w, unsigned short* __restrict__ wt)
{
    int idx = blockIdx.x * 256 + threadIdx.x;   // 64*32
    if (idx >= 64 * 32) return;
    int co = idx >> 5, k = idx & 31;
    wt[idx] = (k < 27) ? f2b(w[co * 27 + k]) : 0;
}

// ---------------------------------------------------------------------------
// Layer 0 fused: halo->LDS, im2col->LDS, K=32 MFMA, bf16 NHWC out.
// ---------------------------------------------------------------------------
__global__ __launch_bounds__(256) void conv_first_fused(
    const float* __restrict__ x, const unsigned short* __restrict__ wt,
    const float* __restrict__ bias, unsigned short* __restrict__ out)
{
    __shared__ float xf[3][18][20];
    __shared__ unsigned short col[256][36];

    const int tid = threadIdx.x;
    const int flat = blockIdx.x;
    const int swz = (flat & 7) * 128 + (flat >> 3);
    const int b = swz >> 8, remb = swz & 255;
    const int h0 = (remb >> 4) * 16, w0 = (remb & 15) * 16;

    const int lane = tid & 63, wid = tid >> 6;
    const int m16 = lane & 15, kg = lane >> 4;

    s16x8 a[4];
    float4 bv[4];
#pragma unroll
    for (int mf = 0; mf < 4; ++mf) {
        a[mf] = *(const s16x8*)(wt + (mf * 16 + m16) * 32 + kg * 8);
        bv[mf] = *(const float4*)(bias + mf * 16 + kg * 4);
    }

#pragma unroll 1
    for (int idx = tid; idx < 972; idx += 256) {
        const int ci = idx / 324, rem2 = idx - ci * 324;
        const int row = rem2 / 18, colw = rem2 - row * 18;
        const int gh = h0 + row - 1, gw = w0 + colw - 1;
        float v = 0.f;
        if ((unsigned)gh < HH && (unsigned)gw < WW)
            v = x[(((size_t)b * 3 + ci) * HH + gh) * WW + gw];
        xf[ci][row][colw] = v;
    }
    __syncthreads();

    {
        const int h = tid >> 4, w = tid & 15;
        unsigned short kv[32];
#pragma unroll
        for (int ci = 0; ci < 3; ++ci)
#pragma unroll
            for (int kh = 0; kh < 3; ++kh)
#pragma unroll
                for (int kw = 0; kw < 3; ++kw)
                    kv[ci * 9 + kh * 3 + kw] = f2b(xf[ci][h + kh][w + kw]);
#pragma unroll
        for (int k = 27; k < 32; ++k) kv[k] = 0;
#pragma unroll
        for (int q = 0; q < 4; ++q)
            *(uint4*)&col[tid][q * 8] = *(const uint4*)(kv + q * 8);
    }
    __syncthreads();

#pragma unroll
    for (int t = 0; t < 4; ++t) {
        const int p = wid * 64 + t * 16 + m16;
        s16x8 bfr = *(const s16x8*)&col[p][kg * 8];
#pragma unroll
        for (int mf = 0; mf < 4; ++mf) {
            f32x4 c = (f32x4)(0.f);
            c = __builtin_amdgcn_mfma_f32_16x16x32_bf16(a[mf], bfr, c, 0, 0, 0);
            unsigned short pk[4];
#pragma unroll
            for (int e = 0; e < 4; ++e) {
                float v = c[e] + (&bv[mf].x)[e];
                v = v >= 0.f ? v : 0.1f * v;
                pk[e] = f2b(v);
            }
            const int h = h0 + (p >> 4), w = w0 + (p & 15);
            *(ushort4*)(out + (((size_t)b * HH + h) * WW + w) * NFC + mf * 16 + kg * 4)
                = *(ushort4*)pk;
        }
    }
}

// ---------------------------------------------------------------------------
// Persistent MFMA conv (round 15 = round 11 + two fixes):
//  - 256 blocks, 1/CU; block owns 4 tiles; weights in LDS; tiles dbuf'd
//  - 512 thr = 8 waves (2/SIMD); wave = 64co x 2 rows; g+1 parity prefetch
//  - FIX 1: border staging two-phase (6 loads in flight, not 1-deep serial)
//  - FIX 2: epilogue 16B stores via lane^16 pairing (write-amp 2x -> ~1x)
// ---------------------------------------------------------------------------
template <int MFRAGS, bool PERB, bool BIAS, bool LRELU, bool NOISE, bool OUTF32>
__global__ __launch_bounds__(512, 1) void mconv(
    const unsigned short* __restrict__ in, const unsigned short* __restrict__ wt,
    const float* __restrict__ bias, const float* __restrict__ noise,
    const float* __restrict__ wnp, void* __restrict__ outv)
{
    constexpr int COP = MFRAGS * 16;
    constexpr int WELEM = 9 * COP * NFC;
    constexpr int NWDMA = WELEM * 2 / 1024;
    __shared__ unsigned short wl[WELEM];          // 73728 B (COP=64)
    __shared__ uint4 xs[2][18 * 18 * 8];          // 82944 B

    const int tid = threadIdx.x;
    const int lane = tid & 63, wid = tid >> 6;    // wid 0..7
    const int m16 = lane & 15, kg = lane >> 4;

    const int hw = blockIdx.x;                    // 0..255
    const int n = (hw & 7) * 32 + (hw >> 3);      // XCD-chunked logical id
    const int b = n >> 6;

    // ---- stage weights once ----
    const unsigned short* wsrc = PERB ? wt + (size_t)b * WELEM : wt;
    for (int i = wid; i < NWDMA; i += 8) {
        const unsigned short* gp = wsrc + i * 512 + (lane >> 3) * 64
                                   + (((lane & 7) ^ (lane >> 3)) << 3);
        __builtin_amdgcn_global_load_lds(
            (const GLOBAL_AS void*)gp, (LDS_AS void*)(wl + i * 512), 16, 0, 0);
    }

    auto stage_tile = [&](int tt, uint4* buf) {
        const int remb = tt & 255;
        const int th = remb >> 4, tw = remb & 15;
        const int h0 = th * 16, w0 = tw * 16;
        const bool interior = (th > 0) && (th < 15) && (tw > 0) && (tw < 15);
        if (interior) {
            for (int i = wid; i < 54; i += 8) {
                const int row = i / 3, part = i - row * 3;
                const int j0 = (part == 0) ? -1 : (part == 1) ? 7 : 9;
                const int gh = h0 + row - 1;
                const int j = j0 + (lane >> 3);
                const int gw = w0 + j;
                const int w = j + 1;
                const unsigned short* gp = in + (((size_t)b * HH + gh) * WW + gw) * NFC
                                              + ((lane & 7) ^ (w & 7)) * 8;
                uint4* lp = buf + (size_t)(row * 18 + (j0 + 1)) * 8;
                __builtin_amdgcn_global_load_lds(
                    (const GLOBAL_AS void*)gp, (LDS_AS void*)lp, 16, 0, 0);
            }
        } else {
            // FIX 1: two-phase border staging, 6 loads in flight
            uint4 u[6];
#pragma unroll
            for (int i = 0; i < 6; ++i) {
                const int idx = tid + i * 512;
                u[i] = make_uint4(0, 0, 0, 0);
                if (idx < 2592) {
                    const int row = idx / 144, rem2 = idx - row * 144;
                    const int w = rem2 >> 3, slot = rem2 & 7;
                    const int gh = h0 + row - 1, gw = w0 + w - 1;
                    if ((unsigned)gh < HH && (unsigned)gw < WW)
                        u[i] = *(const uint4*)(in + (((size_t)b * HH + gh) * WW + gw) * NFC + slot * 8);
                }
            }
#pragma unroll
            for (int i = 0; i < 6; ++i) {
                const int idx = tid + i * 512;
                if (idx < 2592) {
                    const int row = idx / 144, rem2 = idx - row * 144;
                    const int w = rem2 >> 3, slot = rem2 & 7;
                    buf[(row * 18 + w) * 8 + (slot ^ (w & 7))] = u[i];
                }
            }
        }
    };

    stage_tile(n * 4, xs[0]);
    __syncthreads();

    const float wn = NOISE ? wnp[0] : 0.f;

#pragma unroll 1
    for (int k = 0; k < 4; ++k) {
        const int tt = n * 4 + k;
        const int remb = tt & 255;
        const int h0 = (remb >> 4) * 16, w0 = (remb & 15) * 16;
        const uint4* buf = xs[k & 1];

        if (k < 3) stage_tile(tt + 1, xs[(k + 1) & 1]);

        f32x4 acc[MFRAGS][2];
#pragma unroll
        for (int mf = 0; mf < MFRAGS; ++mf)
#pragma unroll
            for (int r = 0; r < 2; ++r) acc[mf][r] = (f32x4)(0.f);

        s16x8 abuf[2][MFRAGS];
        s16x8 bbuf[2][2];

        auto LOADG = [&](int g, int par) {
            const int tap = g >> 1, half = g & 1;
            const int kh = tap / 3, kw = tap - kh * 3;
            const int lw = m16 + kw;
            const int slot = (half * 4 + kg) ^ (lw & 7);
#pragma unroll
            for (int mf = 0; mf < MFRAGS; ++mf) {
                const int eoff = (tap * COP + mf * 16 + m16) * NFC
                                 + (((half * 4 + kg) * 8) ^ ((m16 & 7) << 3));
                abuf[par][mf] = *(const s16x8*)(wl + eoff);
            }
#pragma unroll
            for (int r = 0; r < 2; ++r) {
                const int lrow = wid * 2 + r + kh;
                bbuf[par][r] = *(const s16x8*)&buf[(lrow * 18 + lw) * 8 + slot];
            }
        };

        LOADG(0, 0);
#pragma unroll
        for (int g = 0; g < 18; ++g) {
            if (g + 1 < 18) LOADG(g + 1, (g + 1) & 1);
#pragma unroll
            for (int r = 0; r < 2; ++r)
#pragma unroll
                for (int mf = 0; mf < MFRAGS; ++mf)
                    acc[mf][r] = __builtin_amdgcn_mfma_f32_16x16x32_bf16(
                        abuf[g & 1][mf], bbuf[g & 1][r], acc[mf][r], 0, 0, 0);
        }

        // ---- epilogue: wave owns rows wid*2, wid*2+1 ----
        const int wcol = w0 + m16;
#pragma unroll
        for (int r = 0; r < 2; ++r) {
            const int h = h0 + wid * 2 + r;
            float nz = 0.f;
            if (NOISE) nz = noise[((size_t)b * HH + h) * WW + wcol];

            if (!OUTF32) {
                // pack all mf first
                uint2 pkk[MFRAGS];
#pragma unroll
                for (int mf = 0; mf < MFRAGS; ++mf) {
                    const int cob = mf * 16 + kg * 4;
                    f32x4 v = acc[mf][r];
                    float4 bvv = make_float4(0.f, 0.f, 0.f, 0.f);
                    if (BIAS) bvv = *(const float4*)(bias + cob);
                    unsigned short pk[4];
#pragma unroll
                    for (int e = 0; e < 4; ++e) {
                        float t = v[e] + (BIAS ? (&bvv.x)[e] : 0.f);
                        if (NOISE) t += wn * nz;
                        if (LRELU) t = t >= 0.f ? t : 0.1f * t;
                        pk[e] = f2b(t);
                    }
                    pkk[mf] = *(uint2*)pk;
                }
                // FIX 2: pair lanes kg <-> kg^1 (lane^16) into 16B stores
                unsigned short* ob = (unsigned short*)outv;
                unsigned short* obp = ob + (((size_t)b * HH + h) * WW + wcol) * NFC;
#pragma unroll
                for (int mf = 0; mf < MFRAGS; ++mf) {
                    uint2 own = pkk[mf];
                    uint2 part;
                    part.x = __shfl_xor((int)own.x, 16);
                    part.y = __shfl_xor((int)own.y, 16);
                    uint2 lo = (kg & 1) ? part : own;   // co (kg&~1)*4 .. +3
                    uint2 hi = (kg & 1) ? own : part;   // co +4 .. +7
                    if (((mf >> 1) & 1) == (kg & 1)) {
                        const int cob16 = mf * 16 + (kg & ~1) * 4;
                        uint4 val = make_uint4(lo.x, lo.y, hi.x, hi.y);
                        *(uint4*)(obp + cob16) = val;
                    }
                }
            } else {
#pragma unroll
                for (int mf = 0; mf < MFRAGS; ++mf) {
                    const int cob = mf * 16 + kg * 4;
                    f32x4 v = acc[mf][r];
                    float4 bvv = make_float4(0.f, 0.f, 0.f, 0.f);
                    if (BIAS) bvv = *(const float4*)(bias + cob);
                    float* of = (float*)outv;
#pragma unroll
                    for (int e = 0; e < 4; ++e) {
                        float t = v[e] + (BIAS ? (&bvv.x)[e] : 0.f);
                        if (NOISE) t += wn * nz;
                        if (LRELU) t = t >= 0.f ? t : 0.1f * t;
                        int co = cob + e;
                        if (co < 3)
                            of[(((size_t)b * 3 + co) * HH + h) * WW + wcol] = t;
                    }
                }
            }
        }
        __syncthreads();
    }
}

// ---------------------------------------------------------------------------
extern "C" void kernel_launch(void* const* d_in, const int* in_sizes, int n_in,
                              void* d_out, int out_size, void* d_ws, size_t ws_size,
                              hipStream_t stream)
{
    auto F = [&](int i) { return (const float*)d_in[i]; };
    const float* x       = F(0);
    const float* emb     = F(1);
    const float* noise[3] = {F(2), F(3), F(4)};
    const float* w_first = F(5);  const float* b_first = F(6);
    const float* w_hr[5] = {F(7), F(9), F(11), F(13), F(15)};
    const float* b_hr[5] = {F(8), F(10), F(12), F(14), F(16)};
    const float* w_last  = F(17); const float* b_last = F(18);
    const float *m_mw[3], *m_mb[3], *m_w[3], *m_cw[3], *m_cb[3], *m_wn[3];
    for (int i = 0; i < 3; ++i) {
        int o = 19 + 6 * i;
        m_mw[i] = F(o); m_mb[i] = F(o + 1); m_w[i] = F(o + 2);
        m_cw[i] = F(o + 3); m_cb[i] = F(o + 4); m_wn[i] = F(o + 5);
    }

    const size_t ACT  = (size_t)NB * HH * WW * NFC;
    const size_t MODW = (size_t)NB * 9 * NFC * NFC;
    const size_t FIXW = (size_t)9 * NFC * NFC;
    unsigned short* act0 = (unsigned short*)d_ws;
    unsigned short* act1 = act0 + ACT;
    unsigned short* wmod = act1 + ACT;
    unsigned short* wfix = wmod + 3 * MODW;
    unsigned short* wlast = wfix + 8 * FIXW;
    unsigned short* wfirst = wlast + 9 * 16 * NFC;

    modw3_kernel<<<dim3(NFC, NB, 3), NFC, 0, stream>>>(
        emb, m_mw[0], m_mb[0], m_w[0], m_mw[1], m_mb[1], m_w[1],
        m_mw[2], m_mb[2], m_w[2], wmod, MODW);
    fixw8_kernel<<<dim3(144, 8), 256, 0, stream>>>(
        m_cw[0], m_cw[1], m_cw[2], w_hr[0], w_hr[1], w_hr[2], w_hr[3], w_hr[4], wfix);
    fixw_last_kernel<<<(9 * 16 * 64 + 255) / 256, 256, 0, stream>>>(w_last, wlast);
    firstw_kernel<<<8, 256, 0, stream>>>(w_first, wfirst);

    conv_first_fused<<<1024, 256, 0, stream>>>(x, wfirst, b_first, act0);

    const int grid = 256;
    unsigned short* cur = act0;
    unsigned short* nxt = act1;
    auto swap = [&]() { unsigned short* t = cur; cur = nxt; nxt = t; };

    for (int i = 0; i < 3; ++i) {
        mconv<4, true, false, false, true, false>
            <<<grid, 512, 0, stream>>>(cur, wmod + i * MODW, nullptr, noise[i], m_wn[i], nxt);
        swap();
        mconv<4, false, true, true, false, false>
            <<<grid, 512, 0, stream>>>(cur, wfix + i * FIXW, m_cb[i], nullptr, nullptr, nxt);
        swap();
        mconv<4, false, true, false, false, false>
            <<<grid, 512, 0, stream>>>(cur, wfix + (3 + i) * FIXW, b_hr[i], nullptr, nullptr, nxt);
        swap();
    }
    mconv<4, false, true, false, false, false>
        <<<grid, 512, 0, stream>>>(cur, wfix + 6 * FIXW, b_hr[3], nullptr, nullptr, nxt);
    swap();
    mconv<4, false, true, false, false, false>
        <<<grid, 512, 0, stream>>>(cur, wfix + 7 * FIXW, b_hr[4], nullptr, nullptr, nxt);
    swap();
    mconv<1, false, true, false, false, true>
        <<<grid, 512, 0, stream>>>(cur, wlast, b_last, nullptr, nullptr, d_out);
}